// Round 7
// baseline (327.872 us; speedup 1.0000x reference)
//
#include <hip/hip_runtime.h>
#include <math.h>

#define SB 64
#define SS 512
#define SH 768
#define NT 36
#define TSTART 34
#define TSTOP 35
#define NC 16
#define CL 32
#define APAD 40

#define CFENCE() asm volatile("" ::: "memory")

__device__ __forceinline__ float wave_max_f(float v) {
#pragma unroll
    for (int off = 32; off > 0; off >>= 1) v = fmaxf(v, __shfl_xor(v, off, 64));
    return v;
}
__device__ __forceinline__ float wave_sum_f(float v) {
#pragma unroll
    for (int off = 32; off > 0; off >>= 1) v += __shfl_xor(v, off, 64);
    return v;
}
__device__ __forceinline__ float bcast0(float v) {
    return __uint_as_float(__builtin_amdgcn_readfirstlane(__float_as_uint(v)));
}

// ---------------- emissions: logits = leaky_relu(gather(x) @ W + b) ----------------
// 512 blocks x 256 thr. lane = row (64 rows/block), wave w = tags [9w, 9w+9).
// x rows staged ONCE per block via async global_load_lds gather (dedups the 4x
// per-wave re-read through L1); W streamed via wave-uniform scalar loads.
extern "C" __global__ __launch_bounds__(256, 4) void k_emit(
    const float* __restrict__ x1, const int* __restrict__ hidx,
    const float* __restrict__ W, const float* __restrict__ bias,
    float* __restrict__ emit, float* __restrict__ out0)
{
    __shared__ float4 xs4[2][16][64];   // 32 KB: [buf][slot(4h)][row]
    __shared__ float  red[4][64][10];   // 10 KB: [wave][row][9 tags + pad]

    int tid  = threadIdx.x;
    int lane = tid & 63;
    int w    = __builtin_amdgcn_readfirstlane(tid >> 6);
    int gr   = blockIdx.x * 64 + lane;
    int b    = gr >> 9;
    const float* xb = x1 + (size_t)(b * SS + hidx[gr]) * SH;

    if (blockIdx.x == 0 && tid == 0) out0[0] = 0.f;   // loss accumulator

    auto stage = [&](int c, int f) {
#pragma unroll
        for (int s = 0; s < 4; ++s) {
            int q = w * 4 + s;   // wave-uniform slot
            __builtin_amdgcn_global_load_lds(
                (const __attribute__((address_space(1))) void*)(xb + c * 64 + q * 4),
                (__attribute__((address_space(3))) void*)&xs4[f][q][0], 16, 0, 0);
        }
    };

    int j0 = w * 9;
    float acc[9];
#pragma unroll
    for (int j = 0; j < 9; ++j) acc[j] = 0.f;

    stage(0, 0);
    int f = 0;
    for (int c = 0; c < 12; ++c) {
        __syncthreads();                  // chunk c staged
        if (c < 11) stage(c + 1, f ^ 1);  // async prefetch
#pragma unroll 4
        for (int s = 0; s < 16; ++s) {
            float4 xv = xs4[f][s][lane];
            const float* wr = W + (size_t)(c * 64 + s * 4) * NT + j0;  // s_load
#pragma unroll
            for (int j = 0; j < 9; ++j) acc[j] += xv.x * wr[j];
#pragma unroll
            for (int j = 0; j < 9; ++j) acc[j] += xv.y * wr[NT + j];
#pragma unroll
            for (int j = 0; j < 9; ++j) acc[j] += xv.z * wr[2 * NT + j];
#pragma unroll
            for (int j = 0; j < 9; ++j) acc[j] += xv.w * wr[3 * NT + j];
        }
        f ^= 1;
    }

#pragma unroll
    for (int j = 0; j < 9; ++j) red[w][lane][j] = acc[j] + bias[j0 + j];
    __syncthreads();

    // coalesced epilogue: 2304 consecutive floats per block
    float* ob = emit + (size_t)blockIdx.x * 64 * NT;
#pragma unroll
    for (int k = 0; k < 9; ++k) {
        int i  = tid + k * 256;
        int r  = i / NT, cx = i - r * NT;
        int ww = cx / 9, jj = cx - ww * 9;
        float v = red[ww][r][jj];
        ob[i] = v > 0.f ? v : 0.01f * v;
    }
}

// ---------------- chunked CRF scan, half-split ----------------
// 256 blocks x 576 thr (9 waves). block = (kind, b, half). Wave w owns chunk
// c = 8h-1+w: pass0 (guess seed) -> barrier -> pass1 (seeded by wave w-1's
// pass0 profile; exact seed for c==0). Half-boundary chunk's pass0 computed
// redundantly (h=1 wave0 = chunk 7). Scan math identical to R6.
extern "C" __global__ __launch_bounds__(576, 1) void k_scan2(
    const float* __restrict__ emit, const int* __restrict__ hidx,
    const float* __restrict__ trans,
    float* __restrict__ dls_g, float* __restrict__ lse_g,
    float* __restrict__ score_g, int* __restrict__ ltag_g,
    unsigned char* __restrict__ bp)
{
    __shared__ float  els[9 * 1152];   // 41.5 KB: 9 chunk slots
    __shared__ float  trl[NT * NT];    // 5.2 KB
    __shared__ float  Apro[9][APAD];   // pass-0 end profiles
    __shared__ float4 bc4[9][16];      // per-wave broadcast buffers

    int tid  = threadIdx.x;
    int lane = tid & 63;
    int w    = __builtin_amdgcn_readfirstlane(tid >> 6);   // 0..8
    int gid  = blockIdx.x;
    int kind = gid >> 7;
    int b    = (gid >> 1) & 63;
    int h    = gid & 1;
    int c    = 8 * h - 1 + w;          // this wave's chunk (-1 => idle)
    int slot = h ? w : (w - 1);
    const float* eb = emit + (size_t)b * SS * NT;

    // stage own chunk's emissions (4608 B): 4x16B + 2x4B async DMA
    float* cls = els + slot * 1152;
    if (c >= 0) {
        const float* src = eb + (size_t)c * CL * NT;
#pragma unroll
        for (int i = 0; i < 4; ++i) {
            __builtin_amdgcn_global_load_lds(
                (const __attribute__((address_space(1))) void*)(src + i * 256 + lane * 4),
                (__attribute__((address_space(3))) void*)(cls + i * 256), 16, 0, 0);
        }
        __builtin_amdgcn_global_load_lds(
            (const __attribute__((address_space(1))) void*)(src + 1024 + lane),
            (__attribute__((address_space(3))) void*)(cls + 1024), 4, 0, 0);
        __builtin_amdgcn_global_load_lds(
            (const __attribute__((address_space(1))) void*)(src + 1088 + lane),
            (__attribute__((address_space(3))) void*)(cls + 1088), 4, 0, 0);
    }
    for (int i = tid; i < NT * NT; i += 576) trl[i] = trans[i];

    int  jj  = lane < NT ? lane : NT - 1;
    bool act = lane < NT;

    // xlen
    int xm = 0;
    const int* hb = hidx + b * SS;
#pragma unroll
    for (int k = 0; k < SS / 64; ++k) xm = max(xm, hb[lane + 64 * k]);
#pragma unroll
    for (int off = 32; off > 0; off >>= 1) xm = max(xm, __shfl_xor(xm, off, 64));
    int xlen = xm;
    int cl   = (xlen >= 1) ? ((xlen - 1) >> 5) : 0;

    // pass-0 seed from GLOBAL (before barrier)
    float seedp0 = -1e30f;
    if (c == 0)     seedp0 = act ? (eb[jj] + trans[TSTART * NT + jj]) : -1e30f;
    else if (c > 0) seedp0 = act ? eb[(size_t)(c * CL - 1) * NT + jj] : -1e30f;

    int tb = c * CL; if (tb < 1) tb = 1;
    int te = (c + 1) * CL; if (te > xlen) te = xlen; te -= 1;   // inclusive

    __syncthreads();   // els + trl staged (drains DMA)

    float* bc = (float*)bc4[w];
    int t0 = c * CL;

    float tcol[NT];
#pragma unroll
    for (int i = 0; i < NT; ++i) {
        float tv = trl[i * NT + jj];
        tcol[i] = kind ? tv : __expf(tv);
    }

    auto scan = [&](float alpha, bool dobp) -> float {
        if (kind == 0) {
            for (int t = tb; t <= te; ++t) {
                float e_t = cls[(t - t0) * NT + jj];
                float m = bcast0(alpha);
                float p = __expf(alpha - m);
                bc[lane] = p;
                CFENCE();
                __builtin_amdgcn_wave_barrier();
                float s0 = 0.f, s1 = 0.f, s2 = 0.f, s3 = 0.f;
#pragma unroll
                for (int k = 0; k < 9; ++k) {
                    float4 pv = bc4[w][k];
                    s0 += pv.x * tcol[4 * k];
                    s1 += pv.y * tcol[4 * k + 1];
                    s2 += pv.z * tcol[4 * k + 2];
                    s3 += pv.w * tcol[4 * k + 3];
                }
                CFENCE();
                float anew = m + __logf((s0 + s1) + (s2 + s3)) + e_t;
                alpha = act ? anew : -1e30f;
            }
        } else {
            for (int t = tb; t <= te; ++t) {
                float e_t = cls[(t - t0) * NT + jj];
                bc[lane] = alpha;
                CFENCE();
                __builtin_amdgcn_wave_barrier();
                float b0 = -1e30f, b1 = -1e30f, b2 = -1e30f, b3 = -1e30f;
                int   i0 = 0, i1 = 1, i2 = 2, i3 = 3;
#pragma unroll
                for (int k = 0; k < 9; ++k) {
                    float4 dv = bc4[w][k];
                    float c0 = dv.x + tcol[4 * k];
                    float c1 = dv.y + tcol[4 * k + 1];
                    float c2 = dv.z + tcol[4 * k + 2];
                    float c3 = dv.w + tcol[4 * k + 3];
                    if (c0 > b0) { b0 = c0; i0 = 4 * k; }
                    if (c1 > b1) { b1 = c1; i1 = 4 * k + 1; }
                    if (c2 > b2) { b2 = c2; i2 = 4 * k + 2; }
                    if (c3 > b3) { b3 = c3; i3 = 4 * k + 3; }
                }
                CFENCE();
                float best = b0; int bi = i0;
                if (b1 > best || (b1 == best && i1 < bi)) { best = b1; bi = i1; }
                if (b2 > best || (b2 == best && i2 < bi)) { best = b2; bi = i2; }
                if (b3 > best || (b3 == best && i3 < bi)) { best = b3; bi = i3; }
                float dnew = best + e_t;
                alpha = act ? dnew : -1e30f;
                if (dobp && act)
                    bp[((size_t)b * SS + t) * 64 + jj] = (unsigned char)bi;
            }
        }
        return alpha;
    };

    // ---- pass 0 ----
    float a0 = -1e30f;
    if (c >= 0) {
        a0 = scan(seedp0, false);
        if (act) Apro[w][jj] = a0;
    }
    __syncthreads();

    // ---- pass 1 (waves 1..8, chunks 8h..8h+7) ----
    if (w >= 1 && c <= cl) {
        float a1seed = (c == 0) ? seedp0 : (act ? Apro[w - 1][jj] : -1e30f);
        float a1 = scan(a1seed, kind == 1);

        if (lane == 0) dls_g[((kind << 6) | b) * NC + c] = bcast0(a1) - bcast0(a0);
        if (c == cl) {
            float ff = act ? (a1 + trl[jj * NT + TSTOP]) : -1e30f;
            if (kind == 0) {
                float M = wave_max_f(ff);
                float ssum = wave_sum_f(__expf(ff - M));
                if (lane == 0) lse_g[b] = M + __logf(ssum);
            } else {
                float bv = ff; int bi = lane;
#pragma unroll
                for (int off = 32; off > 0; off >>= 1) {
                    float ov = __shfl_xor(bv, off, 64);
                    int   oi = __shfl_xor(bi, off, 64);
                    if (ov > bv || (ov == bv && oi < bi)) { bv = ov; bi = oi; }
                }
                if (lane == 0) { score_g[b] = bv; ltag_g[b] = bi; }
            }
        }
    }
}

// ---------------- finalize: loss (atomic), score, backtrack ----------------
extern "C" __global__ __launch_bounds__(64) void k_fin(
    const float* __restrict__ emit, const int* __restrict__ hidx,
    const int* __restrict__ tags, const float* __restrict__ trans,
    const float* __restrict__ dls_g, const float* __restrict__ lse_g,
    const float* __restrict__ score_g, const int* __restrict__ ltag_g,
    const unsigned char* __restrict__ bp,
    float* __restrict__ out0, float* __restrict__ path_out,
    float* __restrict__ score_out)
{
    __shared__ unsigned char bpl[SS * 64];   // 32 KB
    int lane = threadIdx.x;
    int b    = blockIdx.x;

    const int4* src = (const int4*)(bp + (size_t)b * SS * 64);
    int4* dst = (int4*)bpl;
    for (int i = lane; i < SS * 4; i += 64) dst[i] = src[i];

    int xm = 0;
    const int* hb = hidx + b * SS;
#pragma unroll
    for (int k = 0; k < SS / 64; ++k) xm = max(xm, hb[lane + 64 * k]);
#pragma unroll
    for (int off = 32; off > 0; off >>= 1) xm = max(xm, __shfl_xor(xm, off, 64));
    int xlen = xm;
    int cl   = (xlen >= 1) ? ((xlen - 1) >> 5) : 0;

    float kf = 0.f, kv = 0.f;
    for (int k = 0; k < cl; ++k) {
        kf += dls_g[(0 * SB + b) * NC + k];
        kv += dls_g[(1 * SB + b) * NC + k];
    }

    const int* tg = tags + b * SS;
    float g = 0.f;
    for (int t = lane; t < SS; t += 64) {
        if (t < xlen) {
            int tt = tg[t];
            g += emit[((size_t)b * SS + t) * NT + tt];
            if (t >= 1) g += trans[tg[t - 1] * NT + tt];
        }
    }
    g = wave_sum_f(g);
    if (lane == 0) {
        int lt = (xlen >= 1) ? tg[xlen - 1] : tg[0];
        float gold = g + trans[TSTART * NT + tg[0]] + trans[lt * NT + TSTOP];
        atomicAdd(out0, (lse_g[b] + kf) - gold);
        score_out[b] = score_g[b] + kv;
    }

    float* op = path_out + (size_t)b * SS;
    for (int t = lane; t < SS; t += 64) if (t >= xlen) op[t] = 0.f;
    int v = ltag_g[b];
    __syncthreads();
    if (xlen >= 1) {
        if (lane == 0) op[xlen - 1] = (float)v;
        int t = xlen - 1;
        while (t >= 1) {
            int n = t < 8 ? t : 8;
            int r0 = bpl[t * 64 + lane];
            int r1 = (n > 1) ? bpl[(t - 1) * 64 + lane] : 0;
            int r2 = (n > 2) ? bpl[(t - 2) * 64 + lane] : 0;
            int r3 = (n > 3) ? bpl[(t - 3) * 64 + lane] : 0;
            int r4 = (n > 4) ? bpl[(t - 4) * 64 + lane] : 0;
            int r5 = (n > 5) ? bpl[(t - 5) * 64 + lane] : 0;
            int r6 = (n > 6) ? bpl[(t - 6) * 64 + lane] : 0;
            int r7 = (n > 7) ? bpl[(t - 7) * 64 + lane] : 0;
            v = __shfl(r0, v, 64); if (lane == 0) op[t - 1] = (float)v;
            if (n > 1) { v = __shfl(r1, v, 64); if (lane == 0) op[t - 2] = (float)v; }
            if (n > 2) { v = __shfl(r2, v, 64); if (lane == 0) op[t - 3] = (float)v; }
            if (n > 3) { v = __shfl(r3, v, 64); if (lane == 0) op[t - 4] = (float)v; }
            if (n > 4) { v = __shfl(r4, v, 64); if (lane == 0) op[t - 5] = (float)v; }
            if (n > 5) { v = __shfl(r5, v, 64); if (lane == 0) op[t - 6] = (float)v; }
            if (n > 6) { v = __shfl(r6, v, 64); if (lane == 0) op[t - 7] = (float)v; }
            if (n > 7) { v = __shfl(r7, v, 64); if (lane == 0) op[t - 8] = (float)v; }
            t -= n;
        }
    }
}

extern "C" void kernel_launch(void* const* d_in, const int* in_sizes, int n_in,
                              void* d_out, int out_size, void* d_ws, size_t ws_size,
                              hipStream_t stream)
{
    const float* x1    = (const float*)d_in[0];
    const int*   hidx  = (const int*)d_in[1];
    const int*   tags  = (const int*)d_in[2];
    const float* W     = (const float*)d_in[3];
    const float* bias  = (const float*)d_in[4];
    const float* trans = (const float*)d_in[5];
    float* out = (float*)d_out;

    float* emit       = (float*)d_ws;                  // 64*512*36 floats
    float* dls_g      = emit + (size_t)SB * SS * NT;   // 2*64*16
    float* lse_g      = dls_g + 2 * SB * NC;           // 64
    float* score_g    = lse_g + SB;                    // 64
    int*   ltag_g     = (int*)(score_g + SB);          // 64
    unsigned char* bp = (unsigned char*)(ltag_g + SB); // 64*512*64 B

    hipLaunchKernelGGL(k_emit, dim3(SB * SS / 64), dim3(256), 0, stream,
                       x1, hidx, W, bias, emit, out);
    hipLaunchKernelGGL(k_scan2, dim3(256), dim3(576), 0, stream,
                       emit, hidx, trans, dls_g, lse_g, score_g, ltag_g, bp);
    hipLaunchKernelGGL(k_fin, dim3(SB), dim3(64), 0, stream,
                       emit, hidx, tags, trans, dls_g, lse_g, score_g, ltag_g,
                       bp, out, out + 1, out + 1 + SB * SS);
}